// Round 15
// baseline (380.858 us; speedup 1.0000x reference)
//
#include <hip/hip_runtime.h>
#include <cstdint>
#include <cstddef>

// Transformer block, B=1 S=4096 D=768 H=12 HD=64 FF=3072.
// Round 26: REVERT to round-24 passing source (r25's O-proj-split-K +
// overlay-move NaN'd; fault not found by audit -> change set rejected per
// rigor). Single forward step kept from r25: down-GEMM z=2 -> z=3
// ((12,64,3)=2304 blocks = 9/CU, 32 K-steps, 37.5MB atomics) — the one
// proven lever (TLP) on the one proven-safe pattern (z-split atomics into
// ln2-pre-initialized h1). Everything else byte-identical to round 24.

#define S_  4096
#define D_  768
#define H_  12
#define HD_ 64
#define FF_ 3072
#define SD_ (4096 * 768)
#define SSCALE 0.18033688011112042f   // 0.125 * log2(e)

typedef short  short8  __attribute__((ext_vector_type(8)));
typedef float  floatx4 __attribute__((ext_vector_type(4)));

__device__ __forceinline__ float bf2f(unsigned short h) {
  union { unsigned int u; float f; } v; v.u = ((unsigned int)h) << 16; return v.f;
}
__device__ __forceinline__ unsigned short f2bf(float f) {
  union { unsigned int u; float f; } v; v.f = f;
  unsigned int u = v.u;
  return (unsigned short)((u + 0x7FFFu + ((u >> 16) & 1u)) >> 16);  // RNE
}
__device__ __forceinline__ unsigned short f2bf_fast(float f) {  // f>=0 finite
  union { unsigned int u; float f; } v; v.f = f;
  return (unsigned short)((v.u + 0x8000u) >> 16);
}
__device__ __forceinline__ unsigned int pack_bf16(float lo, float hi) {
  return (unsigned int)f2bf_fast(lo) | ((unsigned int)f2bf_fast(hi) << 16);
}
__device__ __forceinline__ void gload_lds16(const unsigned short* g, unsigned short* l) {
  __builtin_amdgcn_global_load_lds(
      (const __attribute__((address_space(1))) unsigned int*)g,
      (__attribute__((address_space(3))) unsigned int*)l, 16, 0, 0);
}

// batched transpose-convert of all 6 weight matrices: src[K][N] -> dst[N][K] bf16.
// segs 0-3: 768x768 (144 tiles each); seg 4: 768x3072 (576); seg 5: 3072x768 (576).
__global__ __launch_bounds__(256) void k_cvt_t6(
    const void* s0, const void* s1, const void* s2, const void* s3,
    const void* s4, const void* s5,
    unsigned short* d0, unsigned short* d1, unsigned short* d2,
    unsigned short* d3, unsigned short* d4, unsigned short* d5,
    const int* __restrict__ flagp) {
  __shared__ unsigned short T[64 * 65];
  const int flag = *flagp;
  const int b = blockIdx.x;
  const void* src; unsigned short* dst; int K, N, ti;
  if (b < 576) {
    const int seg = b / 144; ti = b - seg * 144; K = 768; N = 768;
    const void* ss[4] = {s0, s1, s2, s3};
    unsigned short* dd[4] = {d0, d1, d2, d3};
    src = ss[seg]; dst = dd[seg];
  } else if (b < 1152) { ti = b - 576;  K = 768;  N = 3072; src = s4; dst = d4; }
  else                 { ti = b - 1152; K = 3072; N = 768;  src = s5; dst = d5; }
  const int nx = N >> 6;
  const int n0 = (ti % nx) * 64, k0 = (ti / nx) * 64;
  const int t = threadIdx.x;
  const int cl = t & 63, rg = t >> 6;
#pragma unroll
  for (int i = 0; i < 16; ++i) {
    const int kl = rg * 16 + i;
    const size_t si = (size_t)(k0 + kl) * N + n0 + cl;
    T[kl * 65 + cl] = flag ? f2bf(((const float*)src)[si]) : ((const unsigned short*)src)[si];
  }
  __syncthreads();
#pragma unroll
  for (int i = 0; i < 16; ++i) {
    const int nl = rg * 16 + i;
    dst[(size_t)(n0 + nl) * K + k0 + cl] = T[cl * 65 + nl];
  }
}

// all small params -> one contiguous f32 region; also detects dtype and
// publishes flag (p0=ln1w: f32 ones -> 0x3F800000, bf16 ones -> 0x3F803F80).
// ln1w 0, ln1b 768, ln2w 1536, ln2b 2304, bq 3072, bk 3840, bv 4608, bo 5376,
// bdn 6144, bup 6912..9983
__global__ void k_cvt_params(const void* p0, const void* p1, const void* p2, const void* p3,
                             const void* p4, const void* p5, const void* p6, const void* p7,
                             const void* p8, const void* p9,
                             float* __restrict__ dst, int* __restrict__ flagp) {
  const int flag = (((const unsigned int*)p0)[0] == 0x3F800000u) ? 1 : 0;
  int i = blockIdx.x * 256 + threadIdx.x;
  if (i == 0) *flagp = flag;
  if (i >= 9984) return;
  const void* src; int j;
  if (i < 6912) {
    int seg = i / 768; j = i - seg * 768;
    const void* tbl[9] = {p0, p1, p2, p3, p4, p5, p6, p7, p8};
    src = tbl[seg];
  } else { src = p9; j = i - 6912; }
  dst[i] = flag ? ((const float*)src)[j] : bf2f(((const unsigned short*)src)[j]);
}

// ---------------- LayerNorm: one block per row of 768 -> bf16 out.
// Input dtype: flagp ? (*flagp: 1=f32, 0=bf16) : f32 (flagp==nullptr).
// Optional xout: write the f32 copy of the input row (replaces k_cvt_f32).
// Optional acc:  acc[row] = x[row] + bias2 (split-K accumulator pre-init).
__global__ __launch_bounds__(256) void k_ln(const void* __restrict__ xv,
                                            const int* __restrict__ flagp,
                                            const float* __restrict__ w,
                                            const float* __restrict__ b,
                                            unsigned short* __restrict__ out,
                                            float* __restrict__ xout,
                                            const float* __restrict__ bias2,
                                            float* __restrict__ acc) {
  const int row = blockIdx.x, t = threadIdx.x;
  const int flag = flagp ? *flagp : 1;
  const float* xr32 = (const float*)xv + (size_t)row * D_;
  const unsigned short* xr16 = (const unsigned short*)xv + (size_t)row * D_;
  float v0 = flag ? xr32[t]       : bf2f(xr16[t]);
  float v1 = flag ? xr32[t + 256] : bf2f(xr16[t + 256]);
  float v2 = flag ? xr32[t + 512] : bf2f(xr16[t + 512]);
  float s = v0 + v1 + v2;
  float ss = v0 * v0 + v1 * v1 + v2 * v2;
  for (int off = 32; off > 0; off >>= 1) {
    s  += __shfl_down(s, off);
    ss += __shfl_down(ss, off);
  }
  __shared__ float sb[4], ssb[4];
  const int wid = t >> 6, lane = t & 63;
  if (lane == 0) { sb[wid] = s; ssb[wid] = ss; }
  __syncthreads();
  s  = sb[0] + sb[1] + sb[2] + sb[3];
  ss = ssb[0] + ssb[1] + ssb[2] + ssb[3];
  const float mu   = s * (1.0f / D_);
  const float var  = ss * (1.0f / D_) - mu * mu;
  const float rstd = rsqrtf(var + 1e-5f);
  unsigned short* orow = out + (size_t)row * D_;
  orow[t]       = f2bf((v0 - mu) * rstd * w[t]       + b[t]);
  orow[t + 256] = f2bf((v1 - mu) * rstd * w[t + 256] + b[t + 256]);
  orow[t + 512] = f2bf((v2 - mu) * rstd * w[t + 512] + b[t + 512]);
  if (xout) {
    float* xrow = xout + (size_t)row * D_;
    xrow[t] = v0; xrow[t + 256] = v1; xrow[t + 512] = v2;
  }
  if (acc) {
    float* arow = acc + (size_t)row * D_;
    arow[t]       = v0 + bias2[t];
    arow[t + 256] = v1 + bias2[t + 256];
    arow[t + 512] = v2 + bias2[t + 512];
  }
}

// ---------------- 2-phase pipelined GEMM: C[M,N] = A[M,K] @ Wt[N,K]^T + bias
// Double-buffered LDS, stage(t+1) before compute(t), raw s_barrier + vmcnt(0).
// XCD-aware bijective block swizzle (requires total blocks % 8 == 0).
// mode 0: bf16   1: +resid->f32   2: gelu->bf16   3: +resid->d_out per flag
// mode 5: QKV scatter (N=2304, TBN=128): segment is BLOCK-UNIFORM since 128
//         divides 768: nb<768 -> Q (scaled by SSCALE), <1536 -> K,
//         else V^T (packed uint2 rows)
// mode 6: split-K partial (gridDim.z ways over K): f32 atomicAdd into Cout, no bias
template <int TBM, int TBN>
__global__ __launch_bounds__(256) void k_gemm_t(
    const unsigned short* __restrict__ A, const unsigned short* __restrict__ Wt,
    const float* __restrict__ bias, const float* __restrict__ resid,
    void* __restrict__ Cout, int M, int N, int K, int mode, const int* __restrict__ flagp) {
  constexpr int MI = TBM / 32, MJ = TBN / 32;
  __shared__ __align__(16) unsigned short As[2][TBM * 32];
  __shared__ __align__(16) unsigned short Bs[2][TBN * 32];
  const int t = threadIdx.x;
  const int w = t >> 6, lane = t & 63;
  const int quad = lane >> 4, l16 = lane & 15;

  const int gx = gridDim.x, gy = gridDim.y;
  const int nwg = gx * gy * gridDim.z;
  const int id  = blockIdx.x + gx * (blockIdx.y + gy * blockIdx.z);
  const int v   = (id & 7) * (nwg >> 3) + (id >> 3);
  const int vx  = v % gx;
  const int vyz = v / gx;
  const int vy  = vyz % gy;
  const int vz  = vyz / gy;

  const int mb = vy * TBM, nb = vx * TBN;
  const int wm = (w >> 1) * (TBM / 2), wn = (w & 1) * (TBN / 2);
  const int grow = lane >> 2;
  const int gcol = (lane & 3) * 8;

  floatx4 acc[MI][MJ];
#pragma unroll
  for (int i = 0; i < MI; ++i)
#pragma unroll
    for (int j = 0; j < MJ; ++j) acc[i][j] = (floatx4){0.f, 0.f, 0.f, 0.f};

  const int kpb = K / gridDim.z;          // K-range of this z-slice (gz=1 -> full K)
  const int kb0 = kpb * vz;
  const int kend = kb0 + kpb;

  auto stage = [&](int buf, int k0) {
#pragma unroll
    for (int r = 0; r < TBM / 64; ++r) {
      const int ch = r * 4 + w;
      gload_lds16(A + (size_t)(mb + ch * 16 + grow) * K + k0 + gcol, &As[buf][ch * 512]);
    }
#pragma unroll
    for (int r = 0; r < TBN / 64; ++r) {
      const int ch = r * 4 + w;
      gload_lds16(Wt + (size_t)(nb + ch * 16 + grow) * K + k0 + gcol, &Bs[buf][ch * 512]);
    }
  };

  stage(0, kb0);
  asm volatile("s_waitcnt vmcnt(0)" ::: "memory");
  __builtin_amdgcn_s_barrier();

  int cur = 0;
  for (int k0 = kb0; k0 < kend; k0 += 32) {
    if (k0 + 32 < kend) stage(cur ^ 1, k0 + 32);   // prefetch next tile (in flight)

    union { short8 v; uint4 q; } fa[MI], fb[MJ];
#pragma unroll
    for (int i = 0; i < MI; ++i)
      fa[i].q = *(const uint4*)&As[cur][(wm + i * 16 + l16) * 32 + quad * 8];
#pragma unroll
    for (int j = 0; j < MJ; ++j)
      fb[j].q = *(const uint4*)&Bs[cur][(wn + j * 16 + l16) * 32 + quad * 8];
#pragma unroll
    for (int i = 0; i < MI; ++i)
#pragma unroll
      for (int j = 0; j < MJ; ++j)
        acc[i][j] = __builtin_amdgcn_mfma_f32_16x16x32_bf16(fa[i].v, fb[j].v, acc[i][j], 0, 0, 0);

    asm volatile("s_waitcnt vmcnt(0)" ::: "memory");
    __builtin_amdgcn_s_barrier();
    cur ^= 1;
  }

  if (mode == 5) {
    // block-uniform segment (TBN=128 divides 768/1536 boundaries)
    unsigned short* qko = (unsigned short*)Cout;
    if (nb < 1536) {
      unsigned short* dst = (nb < 768) ? qko : qko + SD_;
      const int cb = (nb < 768) ? nb : nb - 768;
      const float qs = (nb < 768) ? SSCALE : 1.0f;   // fold softmax scale into Q
#pragma unroll
      for (int i = 0; i < MI; ++i)
#pragma unroll
        for (int j = 0; j < MJ; ++j) {
          const int col = cb + wn + j * 16 + l16;
          const float bv = bias[nb + wn + j * 16 + l16];
#pragma unroll
          for (int r = 0; r < 4; ++r) {
            const int row = mb + wm + i * 16 + quad * 4 + r;
            dst[(size_t)row * 768 + col] = f2bf((acc[i][j][r] + bv) * qs);
          }
        }
    } else {
      unsigned short* vt = qko + 2 * (size_t)SD_;
#pragma unroll
      for (int i = 0; i < MI; ++i)
#pragma unroll
        for (int j = 0; j < MJ; ++j) {
          const int col = nb - 1536 + wn + j * 16 + l16;
          const float bv = bias[nb + wn + j * 16 + l16];
          const int row0 = mb + wm + i * 16 + quad * 4;
          uint2 pk;
          pk.x = pack_bf16(acc[i][j][0] + bv, acc[i][j][1] + bv);
          pk.y = pack_bf16(acc[i][j][2] + bv, acc[i][j][3] + bv);
          *(uint2*)&vt[(size_t)col * 4096 + row0] = pk;
        }
    }
    return;
  }

  const int flag = (mode == 3) ? *flagp : 0;
#pragma unroll
  for (int i = 0; i < MI; ++i) {
#pragma unroll
    for (int j = 0; j < MJ; ++j) {
      const int col = nb + wn + j * 16 + l16;
      const float bv = (mode == 6) ? 0.f : bias[col];
#pragma unroll
      for (int r = 0; r < 4; ++r) {
        const int row = mb + wm + i * 16 + quad * 4 + r;
        const size_t idx = (size_t)row * N + col;
        float v = acc[i][j][r] + bv;
        if (mode == 0) {
          ((unsigned short*)Cout)[idx] = f2bf(v);
        } else if (mode == 1) {
          ((float*)Cout)[idx] = v + resid[idx];
        } else if (mode == 2) {
          float g = 0.5f * v * (1.0f + erff(v * 0.70710678118f));
          ((unsigned short*)Cout)[idx] = f2bf(g);
        } else if (mode == 6) {
          unsafeAtomicAdd((float*)Cout + idx, v);   // HW global_atomic_add_f32
        } else {
          v += resid[idx];
          if (flag) ((float*)Cout)[idx] = v;
          else      ((unsigned short*)Cout)[idx] = f2bf(v);
        }
      }
    }
  }
}

// final output convert: acc f32 [4096][768] -> d_out (f32 or bf16 per flag)
__global__ __launch_bounds__(256) void k_out(const float* __restrict__ acc,
                                             const int* __restrict__ flagp,
                                             void* __restrict__ out) {
  const int i = (blockIdx.x * 256 + threadIdx.x) * 4;
  const floatx4 v = *(const floatx4*)(acc + i);
  if (*flagp) {
    *(floatx4*)((float*)out + i) = v;
  } else {
    union { unsigned short e[4]; uint2 u; } p;
#pragma unroll
    for (int e = 0; e < 4; ++e) p.e[e] = f2bf(v[e]);
    *(uint2*)((unsigned short*)out + i) = p.u;
  }
}

// ---------------- split-K MFMA flash attention, fixed-max softmax (m==0).
// LDS K/V staging + T14 register prefetch, big-chunks-first, swapped-QK
// packed-P. Q pre-scaled by SSCALE at the QKV epilogue -> exp2(cc) direct.
// All-ones pad-mask fast path: wave 0 computes __all(mreg!=0) per tile ->
// LDS flag -> uniform branch skips m4 load + cndmask on non-causal tiles.
// L via ones-MFMA (4 MFMA/tile on the matrix pipe, r16-verified layout).
#define LK 72
__global__ __launch_bounds__(256) void k_attn_chunk(
    const unsigned short* __restrict__ qb, const unsigned short* __restrict__ kb,
    const unsigned short* __restrict__ vtb, const int* __restrict__ amask,
    unsigned short* __restrict__ Opart, float* __restrict__ Lpart) {
  const int h = blockIdx.y;
  const int x = 79 - (int)blockIdx.x;   // logical chunk; g=3 (16-tile) blocks first
  int g, base;
  if (x < 8)       { g = 0; base = 0; }
  else if (x < 24) { g = 1; base = 8; }
  else if (x < 48) { g = 2; base = 24; }
  else             { g = 3; base = 48; }
  const int rem = x - base;
  const int qt = 8 * g + rem / (g + 1);
  const int c  = rem % (g + 1);
  const int qbase = qt * 128;
  const int kt0 = c * 16;
  const int kt1 = min(kt0 + 16, 2 * qt + 2);

  __shared__ __align__(16) unsigned short Kt[64 * LK];
  __shared__ __align__(16) unsigned short Vt[64 * LK];
  __shared__ __align__(16) unsigned short Ps[128 * LK];
  __shared__ int Mk[64];
  __shared__ int Mka;
  const int t = threadIdx.x;
  const int w = t >> 6, lane = t & 63;
  const int quad = lane >> 4, l16 = lane & 15;
  const int sr = t >> 2, sc = (t & 3) * 16;

  // Q frags straight from global: two 16-row sub-tiles per wave
  union { short8 v; uint4 q; } qf[2][2];
#pragma unroll
  for (int sub = 0; sub < 2; ++sub) {
    const unsigned short* qp =
        qb + (size_t)(qbase + w * 32 + sub * 16 + l16) * D_ + h * HD_ + quad * 8;
    qf[sub][0].q = *(const uint4*)qp;
    qf[sub][1].q = *(const uint4*)(qp + 32);
  }
  short8 onesB;
#pragma unroll
  for (int e = 0; e < 8; ++e) onesB[e] = (short)0x3F80;   // bf16 1.0
  unsigned short* myP = &Ps[w * 32 * LK];

  floatx4 O[2][4], Lacc[2];
#pragma unroll
  for (int sub = 0; sub < 2; ++sub) {
    Lacc[sub] = (floatx4){0.f, 0.f, 0.f, 0.f};
#pragma unroll
    for (int dc = 0; dc < 4; ++dc) O[sub][dc] = (floatx4){0.f, 0.f, 0.f, 0.f};
  }
  const int qcol0 = qbase + w * 32 + l16;              // + sub*16

  // T14 staging registers: tile kt's K/V/mask live here until the ds_write
  uint4 kr0, kr1, vr0, vr1; int mreg = 0;
  auto prefetch = [&](int kt) {
    const int kbase = kt * 64;
    const unsigned short* ks = kb + (size_t)(kbase + sr) * D_ + h * HD_ + sc;
    kr0 = *(const uint4*)ks;
    kr1 = *(const uint4*)(ks + 8);
    const unsigned short* vs = vtb + (size_t)(h * HD_ + sr) * S_ + kbase + sc;
    vr0 = *(const uint4*)vs;
    vr1 = *(const uint4*)(vs + 8);
    if (t < 64) mreg = amask[kbase + t];
  };
  prefetch(kt0);

  for (int kt = kt0; kt < kt1; ++kt) {
    const int kbase = kt * 64;
    // write the staged registers (loaded during the previous tile's compute)
    *(uint4*)&Kt[sr * LK + sc]     = kr0;
    *(uint4*)&Kt[sr * LK + sc + 8] = kr1;
    *(uint4*)&Vt[sr * LK + sc]     = vr0;
    *(uint4*)&Vt[sr * LK + sc + 8] = vr1;
    if (t < 64) {
      Mk[t] = mreg;
      const int am = __all(mreg != 0) ? 1 : 0;   // wave 0, all 64 lanes active
      if (t == 0) Mka = am;
    }
    __syncthreads();
    const bool diag = (kt >= 2 * qt);   // last two k-tiles carry the causal edge
    const bool fast = (Mka != 0) && !diag;

    if (kt + 1 < kt1) prefetch(kt + 1);   // loads fly under the compute below

    // ---- swapped QK + softmax + packed P-store, per 16-k group
#pragma unroll
    for (int kc = 0; kc < 4; ++kc) {
      union { short8 v; uint4 q; } kf[2];
      const unsigned short* p0 = &Kt[(kc * 16 + l16) * LK + quad * 8];
      kf[0].q = *(const uint4*)p0;
      kf[1].q = *(const uint4*)(p0 + 32);
      floatx4 cc[2];
      __builtin_amdgcn_s_setprio(1);
#pragma unroll
      for (int sub = 0; sub < 2; ++sub) {
        cc[sub] = (floatx4){0.f, 0.f, 0.f, 0.f};
        cc[sub] = __builtin_amdgcn_mfma_f32_16x16x32_bf16(kf[0].v, qf[sub][0].v, cc[sub], 0, 0, 0);
        cc[sub] = __builtin_amdgcn_mfma_f32_16x16x32_bf16(kf[1].v, qf[sub][1].v, cc[sub], 0, 0, 0);
      }
      __builtin_amdgcn_s_setprio(0);
      const int kl0 = kc * 16 + quad * 4;          // local k of reg r=0
      if (fast) {
        // no pad mask, no causal edge: P = exp2(S) directly (Q pre-scaled)
#pragma unroll
        for (int sub = 0; sub < 2; ++sub) {
          float p[4];
#pragma unroll
          for (int r = 0; r < 4; ++r)
            p[r] = __builtin_amdgcn_exp2f(cc[sub][r]);
          const uint2 d = {pack_bf16(p[0], p[1]), pack_bf16(p[2], p[3])};
          *(uint2*)&myP[(sub * 16 + l16) * LK + kl0] = d;
        }
      } else {
        const int kg0 = kbase + kl0;               // global k of reg r=0
        const int4 m4 = *(const int4*)&Mk[kl0];    // broadcast within 16-lane group
#pragma unroll
        for (int sub = 0; sub < 2; ++sub) {
          const int qr = qcol0 + sub * 16;
          float p[4];
#pragma unroll
          for (int r = 0; r < 4; ++r) {
            const float e = __builtin_amdgcn_exp2f(cc[sub][r]);
            const int mv = (r == 0) ? m4.x : (r == 1) ? m4.y : (r == 2) ? m4.z : m4.w;
            const bool keep = (mv != 0) && (!diag || (kg0 + r <= qr));
            p[r] = keep ? e : 0.f;
          }
          const uint2 d = {pack_bf16(p[0], p[1]), pack_bf16(p[2], p[3])};
          *(uint2*)&myP[(sub * 16 + l16) * LK + kl0] = d;
        }
      }
    }

    // ---- P A-frags (wave-private round-trip), L via ones-MFMA, PV
    union { short8 v; uint4 q; } pf[2][2];
#pragma unroll
    for (int sub = 0; sub < 2; ++sub) {
      const unsigned short* p0 = &myP[(sub * 16 + l16) * LK + quad * 8];
      pf[sub][0].q = *(const uint4*)p0;
      pf[sub][1].q = *(const uint4*)(p0 + 32);
      Lacc[sub] = __builtin_amdgcn_mfma_f32_16x16x32_bf16(pf[sub][0].v, onesB, Lacc[sub], 0, 0, 0);
      Lacc[sub] = __builtin_amdgcn_mfma_f32_16x16x32_bf16(pf[sub][1].v, onesB, Lacc[sub], 0, 0, 0);
    }
    __builtin_amdgcn_s_setprio(1);
#pragma unroll
    for (int dc = 0; dc < 4; ++dc) {
      union { short8 v; uint4 q; } vf[2];
      const unsigned short* p0 = &Vt[(dc * 16 + l16) * LK + quad * 8];
      vf[0].q = *(const uint4*)p0;
      vf[1].q = *(const uint4*)(p0 + 32);
#pragma unroll
      for (int sub = 0; sub < 2; ++sub) {
        O[sub][dc] = __builtin_amdgcn_mfma_f32_16x16x32_bf16(pf[sub][0].v, vf[0].v, O[sub][dc], 0, 0, 0);
        O[sub][dc] = __builtin_amdgcn_mfma_f32_16x16x32_bf16(pf[sub][1].v, vf[1].v, O[sub][dc], 0, 0, 0);
      }
    }
    __builtin_amdgcn_s_setprio(0);
    __syncthreads();   // all waves done reading Kt/Vt before next ds_write
  }

  // write partials (unnormalized, m==0): 128 rows x 64 per slot
  const size_t slot = (size_t)h * 80 + x;
#pragma unroll
  for (int sub = 0; sub < 2; ++sub) {
#pragma unroll
    for (int dc = 0; dc < 4; ++dc)
#pragma unroll
      for (int r = 0; r < 4; ++r)
        Opart[slot * 8192 + (w * 32 + sub * 16 + quad * 4 + r) * 64 + dc * 16 + l16] =
            f2bf(O[sub][dc][r]);
    if (l16 == 0) {
#pragma unroll
      for (int r = 0; r < 4; ++r)
        Lpart[slot * 128 + w * 32 + sub * 16 + quad * 4 + r] = Lacc[sub][r];
    }
  }
}

// merge <=4 partials per (qt128, h): thread -> (q-row, 32-wide d-half)
__global__ __launch_bounds__(256) void k_attn_merge(
    const unsigned short* __restrict__ Opart, const float* __restrict__ Lpart,
    unsigned short* __restrict__ ob) {
  const int qt = blockIdx.x, h = blockIdx.y;   // qt in [0,32)
  const int t = threadIdx.x;
  const int row = t >> 1, half = (t & 1) * 32;
  const int g = qt >> 3;
  const int nch = g + 1;
  const int cb = h * 80 + 4 * g * (g + 1) + (qt & 7) * (g + 1);
  float L = 0.f;
  float acc[32];
#pragma unroll
  for (int j = 0; j < 32; ++j) acc[j] = 0.f;
  for (int ci = 0; ci < nch; ++ci) {
    L += Lpart[(size_t)(cb + ci) * 128 + row];
    const unsigned short* op = Opart + (size_t)(cb + ci) * 8192 + row * 64 + half;
#pragma unroll
    for (int j4 = 0; j4 < 4; ++j4) {
      union { uint4 v; unsigned short e[8]; } u;
      u.v = *(const uint4*)(op + j4 * 8);
#pragma unroll
      for (int e = 0; e < 8; ++e) acc[j4 * 8 + e] += bf2f(u.e[e]);
    }
  }
  const float inv = 1.f / L;
  unsigned short* orow = ob + (size_t)(qt * 128 + row) * D_ + h * HD_ + half;
#pragma unroll
  for (int j4 = 0; j4 < 4; ++j4) {
    union { uint4 v; unsigned short e[8]; } u;
#pragma unroll
    for (int e = 0; e < 8; ++e) u.e[e] = f2bf(acc[j4 * 8 + e] * inv);
    *(uint4*)(orow + j4 * 8) = u.v;
  }
}

// ---------------- host
extern "C" void kernel_launch(void* const* d_in, const int* in_sizes, int n_in,
                              void* d_out, int out_size, void* d_ws, size_t ws_size,
                              hipStream_t stream) {
  const void* hidden = d_in[0];
  const int*  amask  = (const int*)d_in[1];
  const void* ln1w = d_in[2];  const void* ln1b = d_in[3];
  const void* wq   = d_in[4];  const void* bq   = d_in[5];
  const void* wk   = d_in[6];  const void* bk   = d_in[7];
  const void* wv   = d_in[8];  const void* bv   = d_in[9];
  const void* wo   = d_in[10]; const void* bo   = d_in[11];
  const void* ln2w = d_in[12]; const void* ln2b = d_in[13];
  const void* wup  = d_in[14]; const void* bup  = d_in[15];
  const void* wdn  = d_in[16]; const void* bdn  = d_in[17];

  char* ws = (char*)d_ws;
  size_t off = 0;
  auto alloc = [&](size_t bytes) {
    char* p = ws + off;
    off += (bytes + 255) & ~(size_t)255;
    return p;
  };
  const size_t SD = (size_t)SD_;
  int*            flagp = (int*)alloc(4);
  float*          h1    = (float*)alloc(SD * 4);
  float*          prm   = (float*)alloc(9984 * 4);
  float*          h2    = (float*)alloc(SD * 4);            // also hosts attn partials
  unsigned short* xb    = (unsigned short*)alloc(SD * 2);   // contiguous after h2
  unsigned short* wqkvt = (unsigned short*)alloc((size_t)2304 * 768 * 2);  // [2304][768]
  unsigned short* wot   = (unsigned short*)alloc((size_t)768 * 768 * 2);   // [768][768]
  unsigned short* wupt  = (unsigned short*)alloc((size_t)3072 * 768 * 2);  // [3072][768]
  unsigned short* wdnt  = (unsigned short*)alloc((size_t)768 * 3072 * 2);  // [768][3072]
  unsigned short* big   = (unsigned short*)alloc((size_t)S_ * FF_ * 2);
  unsigned short* qb2 = big;
  unsigned short* kb2 = big + SD;
  unsigned short* vtb = big + 2 * SD;   // V^T [768][4096]
  unsigned short* ab  = big + 3 * SD;
  unsigned short* ffb = big;
  // attention partials overlay dead h2+xb (18.87 MB): Opart 960*8192 bf16 =
  // 15.73 MB + Lpart 960*128 f32 = 0.49 MB = 16.22 MB. FITS.
  unsigned short* Opart = (unsigned short*)h2;
  float*          Lpart = (float*)((char*)h2 + (size_t)960 * 8192 * 2);

  float* f_ln1w = prm;        float* f_ln1b = prm + 768;
  float* f_ln2w = prm + 1536; float* f_ln2b = prm + 2304;
  float* f_bqkv = prm + 3072; float* f_bo = prm + 5376;
  float* f_bdn = prm + 6144;  float* f_bup = prm + 6912;

  k_cvt_params<<<39, 256, 0, stream>>>(ln1w, ln1b, ln2w, ln2b, bq, bk, bv, bo, bdn, bup,
                                       prm, flagp);
  k_cvt_t6<<<1728, 256, 0, stream>>>(wq, wk, wv, wo, wup, wdn,
                                     wqkvt, wqkvt + 768 * 768, wqkvt + 2 * 768 * 768,
                                     wot, wupt, wdnt, flagp);

  // ln1 fused with input convert: reads raw hidden (flag dtype), writes
  // xb (LN output) + h1 (f32 copy of hidden, O-proj residual)
  k_ln<<<S_, 256, 0, stream>>>(hidden, flagp, f_ln1w, f_ln1b, xb, h1, nullptr, nullptr);

  // fused QKV: [4096,768] @ [768,2304] -> scatter Q(scaled),K,V^T
  // <64,128>: (18,64) = 1152 blocks %8==0, 24KB LDS
  k_gemm_t<64, 128><<<dim3(18, 64), 256, 0, stream>>>(
      xb, wqkvt, f_bqkv, nullptr, qb2, S_, 2304, 768, 5, flagp);

  k_attn_chunk<<<dim3(80, 12), 256, 0, stream>>>(qb2, kb2, vtb, amask, Opart, Lpart);
  k_attn_merge<<<dim3(32, 12), 256, 0, stream>>>(Opart, Lpart, ab);

  // O-proj + residual -> h2 (f32)   <64,64>: (12,64) = 768 blocks %8==0
  k_gemm_t<64, 64><<<dim3(12, 64), 256, 0, stream>>>(
      ab, wot, f_bo, h1, h2, S_, 768, 768, 1, flagp);

  // ln2 (h2 is f32: flagp=nullptr); h1 dead -> pre-init acc = h2 + b_down
  k_ln<<<S_, 256, 0, stream>>>(h2, nullptr, f_ln2w, f_ln2b, xb, nullptr, f_bdn, h1);

  // FFN up   <64,128>: (24,64) = 1536 blocks %8==0, 24KB LDS
  k_gemm_t<64, 128><<<dim3(24, 64), 256, 0, stream>>>(
      xb, wupt, f_bup, nullptr, ffb, S_, 3072, 768, 2, flagp);

  // FFN down <64,64> + split-K=3: (12,64,3) = 2304 blocks %8==0 = 9/CU,
  // 32 K-steps/block, 37.5MB atomics into h1
  k_gemm_t<64, 64><<<dim3(12, 64, 3), 256, 0, stream>>>(
      ffb, wdnt, nullptr, nullptr, h1, S_, 768, 3072, 6, flagp);

  // h1 -> d_out per dtype flag
  k_out<<<3072, 256, 0, stream>>>(h1, flagp, d_out);
}

// Round 16
// 368.000 us; speedup vs baseline: 1.0349x; 1.0349x over previous
//
#include <hip/hip_runtime.h>
#include <cstdint>
#include <cstddef>

// Transformer block, B=1 S=4096 D=768 H=12 HD=64 FF=3072.
// Round 27: de-atomize the down-GEMM. r26 post-mortem: z=3 REGRESSED (64 ->
// 71.9us; +12.3MB atomics = +7.5us, occupancy flat) -> atomic write-through
// bytes are the marginal cost, TLP saturated at 6 blocks/CU. Fix: z=2 with
// mode 7 = NON-atomic bf16 partials into h2 (dead after ln2; 2 x 6.29MB fits
// its 12.58MB; every (row,col,z) written exactly once -> no init, no RMW).
// k_out sums h1acc(=h2+bdn) + p0 + p1. Everything else = r24 (best passing,
// 377us).

#define S_  4096
#define D_  768
#define H_  12
#define HD_ 64
#define FF_ 3072
#define SD_ (4096 * 768)
#define SSCALE 0.18033688011112042f   // 0.125 * log2(e)

typedef short  short8  __attribute__((ext_vector_type(8)));
typedef float  floatx4 __attribute__((ext_vector_type(4)));

__device__ __forceinline__ float bf2f(unsigned short h) {
  union { unsigned int u; float f; } v; v.u = ((unsigned int)h) << 16; return v.f;
}
__device__ __forceinline__ unsigned short f2bf(float f) {
  union { unsigned int u; float f; } v; v.f = f;
  unsigned int u = v.u;
  return (unsigned short)((u + 0x7FFFu + ((u >> 16) & 1u)) >> 16);  // RNE
}
__device__ __forceinline__ unsigned short f2bf_fast(float f) {  // f>=0 finite
  union { unsigned int u; float f; } v; v.f = f;
  return (unsigned short)((v.u + 0x8000u) >> 16);
}
__device__ __forceinline__ unsigned int pack_bf16(float lo, float hi) {
  return (unsigned int)f2bf_fast(lo) | ((unsigned int)f2bf_fast(hi) << 16);
}
__device__ __forceinline__ void gload_lds16(const unsigned short* g, unsigned short* l) {
  __builtin_amdgcn_global_load_lds(
      (const __attribute__((address_space(1))) unsigned int*)g,
      (__attribute__((address_space(3))) unsigned int*)l, 16, 0, 0);
}

// batched transpose-convert of all 6 weight matrices: src[K][N] -> dst[N][K] bf16.
// segs 0-3: 768x768 (144 tiles each); seg 4: 768x3072 (576); seg 5: 3072x768 (576).
__global__ __launch_bounds__(256) void k_cvt_t6(
    const void* s0, const void* s1, const void* s2, const void* s3,
    const void* s4, const void* s5,
    unsigned short* d0, unsigned short* d1, unsigned short* d2,
    unsigned short* d3, unsigned short* d4, unsigned short* d5,
    const int* __restrict__ flagp) {
  __shared__ unsigned short T[64 * 65];
  const int flag = *flagp;
  const int b = blockIdx.x;
  const void* src; unsigned short* dst; int K, N, ti;
  if (b < 576) {
    const int seg = b / 144; ti = b - seg * 144; K = 768; N = 768;
    const void* ss[4] = {s0, s1, s2, s3};
    unsigned short* dd[4] = {d0, d1, d2, d3};
    src = ss[seg]; dst = dd[seg];
  } else if (b < 1152) { ti = b - 576;  K = 768;  N = 3072; src = s4; dst = d4; }
  else                 { ti = b - 1152; K = 3072; N = 768;  src = s5; dst = d5; }
  const int nx = N >> 6;
  const int n0 = (ti % nx) * 64, k0 = (ti / nx) * 64;
  const int t = threadIdx.x;
  const int cl = t & 63, rg = t >> 6;
#pragma unroll
  for (int i = 0; i < 16; ++i) {
    const int kl = rg * 16 + i;
    const size_t si = (size_t)(k0 + kl) * N + n0 + cl;
    T[kl * 65 + cl] = flag ? f2bf(((const float*)src)[si]) : ((const unsigned short*)src)[si];
  }
  __syncthreads();
#pragma unroll
  for (int i = 0; i < 16; ++i) {
    const int nl = rg * 16 + i;
    dst[(size_t)(n0 + nl) * K + k0 + cl] = T[cl * 65 + nl];
  }
}

// all small params -> one contiguous f32 region; also detects dtype and
// publishes flag (p0=ln1w: f32 ones -> 0x3F800000, bf16 ones -> 0x3F803F80).
// ln1w 0, ln1b 768, ln2w 1536, ln2b 2304, bq 3072, bk 3840, bv 4608, bo 5376,
// bdn 6144, bup 6912..9983
__global__ void k_cvt_params(const void* p0, const void* p1, const void* p2, const void* p3,
                             const void* p4, const void* p5, const void* p6, const void* p7,
                             const void* p8, const void* p9,
                             float* __restrict__ dst, int* __restrict__ flagp) {
  const int flag = (((const unsigned int*)p0)[0] == 0x3F800000u) ? 1 : 0;
  int i = blockIdx.x * 256 + threadIdx.x;
  if (i == 0) *flagp = flag;
  if (i >= 9984) return;
  const void* src; int j;
  if (i < 6912) {
    int seg = i / 768; j = i - seg * 768;
    const void* tbl[9] = {p0, p1, p2, p3, p4, p5, p6, p7, p8};
    src = tbl[seg];
  } else { src = p9; j = i - 6912; }
  dst[i] = flag ? ((const float*)src)[j] : bf2f(((const unsigned short*)src)[j]);
}

// ---------------- LayerNorm: one block per row of 768 -> bf16 out.
// Input dtype: flagp ? (*flagp: 1=f32, 0=bf16) : f32 (flagp==nullptr).
// Optional xout: write the f32 copy of the input row (replaces k_cvt_f32).
// Optional acc:  acc[row] = x[row] + bias2 (split-K accumulator pre-init).
__global__ __launch_bounds__(256) void k_ln(const void* __restrict__ xv,
                                            const int* __restrict__ flagp,
                                            const float* __restrict__ w,
                                            const float* __restrict__ b,
                                            unsigned short* __restrict__ out,
                                            float* __restrict__ xout,
                                            const float* __restrict__ bias2,
                                            float* __restrict__ acc) {
  const int row = blockIdx.x, t = threadIdx.x;
  const int flag = flagp ? *flagp : 1;
  const float* xr32 = (const float*)xv + (size_t)row * D_;
  const unsigned short* xr16 = (const unsigned short*)xv + (size_t)row * D_;
  float v0 = flag ? xr32[t]       : bf2f(xr16[t]);
  float v1 = flag ? xr32[t + 256] : bf2f(xr16[t + 256]);
  float v2 = flag ? xr32[t + 512] : bf2f(xr16[t + 512]);
  float s = v0 + v1 + v2;
  float ss = v0 * v0 + v1 * v1 + v2 * v2;
  for (int off = 32; off > 0; off >>= 1) {
    s  += __shfl_down(s, off);
    ss += __shfl_down(ss, off);
  }
  __shared__ float sb[4], ssb[4];
  const int wid = t >> 6, lane = t & 63;
  if (lane == 0) { sb[wid] = s; ssb[wid] = ss; }
  __syncthreads();
  s  = sb[0] + sb[1] + sb[2] + sb[3];
  ss = ssb[0] + ssb[1] + ssb[2] + ssb[3];
  const float mu   = s * (1.0f / D_);
  const float var  = ss * (1.0f / D_) - mu * mu;
  const float rstd = rsqrtf(var + 1e-5f);
  unsigned short* orow = out + (size_t)row * D_;
  orow[t]       = f2bf((v0 - mu) * rstd * w[t]       + b[t]);
  orow[t + 256] = f2bf((v1 - mu) * rstd * w[t + 256] + b[t + 256]);
  orow[t + 512] = f2bf((v2 - mu) * rstd * w[t + 512] + b[t + 512]);
  if (xout) {
    float* xrow = xout + (size_t)row * D_;
    xrow[t] = v0; xrow[t + 256] = v1; xrow[t + 512] = v2;
  }
  if (acc) {
    float* arow = acc + (size_t)row * D_;
    arow[t]       = v0 + bias2[t];
    arow[t + 256] = v1 + bias2[t + 256];
    arow[t + 512] = v2 + bias2[t + 512];
  }
}

// ---------------- 2-phase pipelined GEMM: C[M,N] = A[M,K] @ Wt[N,K]^T + bias
// Double-buffered LDS, stage(t+1) before compute(t), raw s_barrier + vmcnt(0).
// XCD-aware bijective block swizzle (requires total blocks % 8 == 0).
// mode 0: bf16   1: +resid->f32   2: gelu->bf16   3: +resid->d_out per flag
// mode 5: QKV scatter (N=2304, TBN=128): segment is BLOCK-UNIFORM since 128
//         divides 768: nb<768 -> Q (scaled by SSCALE), <1536 -> K,
//         else V^T (packed uint2 rows)
// mode 6: split-K partial (gridDim.z ways over K): f32 atomicAdd into Cout
// mode 7: split-K partial, NON-atomic: bf16 partial -> Cout + vz*SD_ (each
//         (row,col,z) written exactly once; merged in k_out)
template <int TBM, int TBN>
__global__ __launch_bounds__(256) void k_gemm_t(
    const unsigned short* __restrict__ A, const unsigned short* __restrict__ Wt,
    const float* __restrict__ bias, const float* __restrict__ resid,
    void* __restrict__ Cout, int M, int N, int K, int mode, const int* __restrict__ flagp) {
  constexpr int MI = TBM / 32, MJ = TBN / 32;
  __shared__ __align__(16) unsigned short As[2][TBM * 32];
  __shared__ __align__(16) unsigned short Bs[2][TBN * 32];
  const int t = threadIdx.x;
  const int w = t >> 6, lane = t & 63;
  const int quad = lane >> 4, l16 = lane & 15;

  const int gx = gridDim.x, gy = gridDim.y;
  const int nwg = gx * gy * gridDim.z;
  const int id  = blockIdx.x + gx * (blockIdx.y + gy * blockIdx.z);
  const int v   = (id & 7) * (nwg >> 3) + (id >> 3);
  const int vx  = v % gx;
  const int vyz = v / gx;
  const int vy  = vyz % gy;
  const int vz  = vyz / gy;

  const int mb = vy * TBM, nb = vx * TBN;
  const int wm = (w >> 1) * (TBM / 2), wn = (w & 1) * (TBN / 2);
  const int grow = lane >> 2;
  const int gcol = (lane & 3) * 8;

  floatx4 acc[MI][MJ];
#pragma unroll
  for (int i = 0; i < MI; ++i)
#pragma unroll
    for (int j = 0; j < MJ; ++j) acc[i][j] = (floatx4){0.f, 0.f, 0.f, 0.f};

  const int kpb = K / gridDim.z;          // K-range of this z-slice (gz=1 -> full K)
  const int kb0 = kpb * vz;
  const int kend = kb0 + kpb;

  auto stage = [&](int buf, int k0) {
#pragma unroll
    for (int r = 0; r < TBM / 64; ++r) {
      const int ch = r * 4 + w;
      gload_lds16(A + (size_t)(mb + ch * 16 + grow) * K + k0 + gcol, &As[buf][ch * 512]);
    }
#pragma unroll
    for (int r = 0; r < TBN / 64; ++r) {
      const int ch = r * 4 + w;
      gload_lds16(Wt + (size_t)(nb + ch * 16 + grow) * K + k0 + gcol, &Bs[buf][ch * 512]);
    }
  };

  stage(0, kb0);
  asm volatile("s_waitcnt vmcnt(0)" ::: "memory");
  __builtin_amdgcn_s_barrier();

  int cur = 0;
  for (int k0 = kb0; k0 < kend; k0 += 32) {
    if (k0 + 32 < kend) stage(cur ^ 1, k0 + 32);   // prefetch next tile (in flight)

    union { short8 v; uint4 q; } fa[MI], fb[MJ];
#pragma unroll
    for (int i = 0; i < MI; ++i)
      fa[i].q = *(const uint4*)&As[cur][(wm + i * 16 + l16) * 32 + quad * 8];
#pragma unroll
    for (int j = 0; j < MJ; ++j)
      fb[j].q = *(const uint4*)&Bs[cur][(wn + j * 16 + l16) * 32 + quad * 8];
#pragma unroll
    for (int i = 0; i < MI; ++i)
#pragma unroll
      for (int j = 0; j < MJ; ++j)
        acc[i][j] = __builtin_amdgcn_mfma_f32_16x16x32_bf16(fa[i].v, fb[j].v, acc[i][j], 0, 0, 0);

    asm volatile("s_waitcnt vmcnt(0)" ::: "memory");
    __builtin_amdgcn_s_barrier();
    cur ^= 1;
  }

  if (mode == 5) {
    // block-uniform segment (TBN=128 divides 768/1536 boundaries)
    unsigned short* qko = (unsigned short*)Cout;
    if (nb < 1536) {
      unsigned short* dst = (nb < 768) ? qko : qko + SD_;
      const int cb = (nb < 768) ? nb : nb - 768;
      const float qs = (nb < 768) ? SSCALE : 1.0f;   // fold softmax scale into Q
#pragma unroll
      for (int i = 0; i < MI; ++i)
#pragma unroll
        for (int j = 0; j < MJ; ++j) {
          const int col = cb + wn + j * 16 + l16;
          const float bv = bias[nb + wn + j * 16 + l16];
#pragma unroll
          for (int r = 0; r < 4; ++r) {
            const int row = mb + wm + i * 16 + quad * 4 + r;
            dst[(size_t)row * 768 + col] = f2bf((acc[i][j][r] + bv) * qs);
          }
        }
    } else {
      unsigned short* vt = qko + 2 * (size_t)SD_;
#pragma unroll
      for (int i = 0; i < MI; ++i)
#pragma unroll
        for (int j = 0; j < MJ; ++j) {
          const int col = nb - 1536 + wn + j * 16 + l16;
          const float bv = bias[nb + wn + j * 16 + l16];
          const int row0 = mb + wm + i * 16 + quad * 4;
          uint2 pk;
          pk.x = pack_bf16(acc[i][j][0] + bv, acc[i][j][1] + bv);
          pk.y = pack_bf16(acc[i][j][2] + bv, acc[i][j][3] + bv);
          *(uint2*)&vt[(size_t)col * 4096 + row0] = pk;
        }
    }
    return;
  }

  const int flag = (mode == 3) ? *flagp : 0;
#pragma unroll
  for (int i = 0; i < MI; ++i) {
#pragma unroll
    for (int j = 0; j < MJ; ++j) {
      const int col = nb + wn + j * 16 + l16;
      const float bv = (mode == 6 || mode == 7) ? 0.f : bias[col];
#pragma unroll
      for (int r = 0; r < 4; ++r) {
        const int row = mb + wm + i * 16 + quad * 4 + r;
        const size_t idx = (size_t)row * N + col;
        float v = acc[i][j][r] + bv;
        if (mode == 0) {
          ((unsigned short*)Cout)[idx] = f2bf(v);
        } else if (mode == 1) {
          ((float*)Cout)[idx] = v + resid[idx];
        } else if (mode == 2) {
          float g = 0.5f * v * (1.0f + erff(v * 0.70710678118f));
          ((unsigned short*)Cout)[idx] = f2bf(g);
        } else if (mode == 6) {
          unsafeAtomicAdd((float*)Cout + idx, v);   // HW global_atomic_add_f32
        } else if (mode == 7) {
          ((unsigned short*)Cout)[(size_t)vz * SD_ + idx] = f2bf(v);
        } else {
          v += resid[idx];
          if (flag) ((float*)Cout)[idx] = v;
          else      ((unsigned short*)Cout)[idx] = f2bf(v);
        }
      }
    }
  }
}

// final merge: out = acc(f32, resid+bias) + p0(bf16) + p1(bf16), per flag
__global__ __launch_bounds__(256) void k_out(const float* __restrict__ acc,
                                             const unsigned short* __restrict__ part,
                                             const int* __restrict__ flagp,
                                             void* __restrict__ out) {
  const int i = (blockIdx.x * 256 + threadIdx.x) * 4;
  const floatx4 v = *(const floatx4*)(acc + i);
  union { uint2 u; unsigned short e[4]; } a, b;
  a.u = *(const uint2*)(part + i);
  b.u = *(const uint2*)(part + SD_ + i);
  float f[4];
#pragma unroll
  for (int e = 0; e < 4; ++e) f[e] = v[e] + bf2f(a.e[e]) + bf2f(b.e[e]);
  if (*flagp) {
    floatx4 o = {f[0], f[1], f[2], f[3]};
    *(floatx4*)((float*)out + i) = o;
  } else {
    union { unsigned short e[4]; uint2 u; } p;
#pragma unroll
    for (int e = 0; e < 4; ++e) p.e[e] = f2bf(f[e]);
    *(uint2*)((unsigned short*)out + i) = p.u;
  }
}

// ---------------- split-K MFMA flash attention, fixed-max softmax (m==0).
// LDS K/V staging + T14 register prefetch, big-chunks-first, swapped-QK
// packed-P. Q pre-scaled by SSCALE at the QKV epilogue -> exp2(cc) direct.
// All-ones pad-mask fast path: wave 0 computes __all(mreg!=0) per tile ->
// LDS flag -> uniform branch skips m4 load + cndmask on non-causal tiles.
// L via ones-MFMA (4 MFMA/tile on the matrix pipe, r16-verified layout).
#define LK 72
__global__ __launch_bounds__(256) void k_attn_chunk(
    const unsigned short* __restrict__ qb, const unsigned short* __restrict__ kb,
    const unsigned short* __restrict__ vtb, const int* __restrict__ amask,
    unsigned short* __restrict__ Opart, float* __restrict__ Lpart) {
  const int h = blockIdx.y;
  const int x = 79 - (int)blockIdx.x;   // logical chunk; g=3 (16-tile) blocks first
  int g, base;
  if (x < 8)       { g = 0; base = 0; }
  else if (x < 24) { g = 1; base = 8; }
  else if (x < 48) { g = 2; base = 24; }
  else             { g = 3; base = 48; }
  const int rem = x - base;
  const int qt = 8 * g + rem / (g + 1);
  const int c  = rem % (g + 1);
  const int qbase = qt * 128;
  const int kt0 = c * 16;
  const int kt1 = min(kt0 + 16, 2 * qt + 2);

  __shared__ __align__(16) unsigned short Kt[64 * LK];
  __shared__ __align__(16) unsigned short Vt[64 * LK];
  __shared__ __align__(16) unsigned short Ps[128 * LK];
  __shared__ int Mk[64];
  __shared__ int Mka;
  const int t = threadIdx.x;
  const int w = t >> 6, lane = t & 63;
  const int quad = lane >> 4, l16 = lane & 15;
  const int sr = t >> 2, sc = (t & 3) * 16;

  // Q frags straight from global: two 16-row sub-tiles per wave
  union { short8 v; uint4 q; } qf[2][2];
#pragma unroll
  for (int sub = 0; sub < 2; ++sub) {
    const unsigned short* qp =
        qb + (size_t)(qbase + w * 32 + sub * 16 + l16) * D_ + h * HD_ + quad * 8;
    qf[sub][0].q = *(const uint4*)qp;
    qf[sub][1].q = *(const uint4*)(qp + 32);
  }
  short8 onesB;
#pragma unroll
  for (int e = 0; e < 8; ++e) onesB[e] = (short)0x3F80;   // bf16 1.0
  unsigned short* myP = &Ps[w * 32 * LK];

  floatx4 O[2][4], Lacc[2];
#pragma unroll
  for (int sub = 0; sub < 2; ++sub) {
    Lacc[sub] = (floatx4){0.f, 0.f, 0.f, 0.f};
#pragma unroll
    for (int dc = 0; dc < 4; ++dc) O[sub][dc] = (floatx4){0.f, 0.f, 0.f, 0.f};
  }
  const int qcol0 = qbase + w * 32 + l16;              // + sub*16

  // T14 staging registers: tile kt's K/V/mask live here until the ds_write
  uint4 kr0, kr1, vr0, vr1; int mreg = 0;
  auto prefetch = [&](int kt) {
    const int kbase = kt * 64;
    const unsigned short* ks = kb + (size_t)(kbase + sr) * D_ + h * HD_ + sc;
    kr0 = *(const uint4*)ks;
    kr1 = *(const uint4*)(ks + 8);
    const unsigned short* vs = vtb + (size_t)(h * HD_ + sr) * S_ + kbase + sc;
    vr0 = *(const uint4*)vs;
    vr1 = *(const uint4*)(vs + 8);
    if (t < 64) mreg = amask[kbase + t];
  };
  prefetch(kt0);

  for (int kt = kt0; kt < kt1; ++kt) {
    const int kbase = kt * 64;
    // write the staged registers (loaded during the previous tile's compute)
    *(uint4*)&Kt[sr * LK + sc]     = kr0;
    *(uint4*)&Kt[sr * LK + sc + 8] = kr1;
    *(uint4*)&Vt[sr * LK + sc]     = vr0;
    *(uint4*)&Vt[sr * LK + sc + 8] = vr1;
    if (t < 64) {
      Mk[t] = mreg;
      const int am = __all(mreg != 0) ? 1 : 0;   // wave 0, all 64 lanes active
      if (t == 0) Mka = am;
    }
    __syncthreads();
    const bool diag = (kt >= 2 * qt);   // last two k-tiles carry the causal edge
    const bool fast = (Mka != 0) && !diag;

    if (kt + 1 < kt1) prefetch(kt + 1);   // loads fly under the compute below

    // ---- swapped QK + softmax + packed P-store, per 16-k group
#pragma unroll
    for (int kc = 0; kc < 4; ++kc) {
      union { short8 v; uint4 q; } kf[2];
      const unsigned short* p0 = &Kt[(kc * 16 + l16) * LK + quad * 8];
      kf[0].q = *(const uint4*)p0;
      kf[1].q = *(const uint4*)(p0 + 32);
      floatx4 cc[2];
      __builtin_amdgcn_s_setprio(1);
#pragma unroll
      for (int sub = 0; sub < 2; ++sub) {
        cc[sub] = (floatx4){0.f, 0.f, 0.f, 0.f};
        cc[sub] = __builtin_amdgcn_mfma_f32_16x16x32_bf16(kf[0].v, qf[sub][0].v, cc[sub], 0, 0, 0);
        cc[sub] = __builtin_amdgcn_mfma_f32_16x16x32_bf16(kf[1].v, qf[sub][1].v, cc[sub], 0, 0, 0);
      }
      __builtin_amdgcn_s_setprio(0);
      const int kl0 = kc * 16 + quad * 4;          // local k of reg r=0
      if (fast) {
        // no pad mask, no causal edge: P = exp2(S) directly (Q pre-scaled)
#pragma unroll
        for (int sub = 0; sub < 2; ++sub) {
          float p[4];
#pragma unroll
          for (int r = 0; r < 4; ++r)
            p[r] = __builtin_amdgcn_exp2f(cc[sub][r]);
          const uint2 d = {pack_bf16(p[0], p[1]), pack_bf16(p[2], p[3])};
          *(uint2*)&myP[(sub * 16 + l16) * LK + kl0] = d;
        }
      } else {
        const int kg0 = kbase + kl0;               // global k of reg r=0
        const int4 m4 = *(const int4*)&Mk[kl0];    // broadcast within 16-lane group
#pragma unroll
        for (int sub = 0; sub < 2; ++sub) {
          const int qr = qcol0 + sub * 16;
          float p[4];
#pragma unroll
          for (int r = 0; r < 4; ++r) {
            const float e = __builtin_amdgcn_exp2f(cc[sub][r]);
            const int mv = (r == 0) ? m4.x : (r == 1) ? m4.y : (r == 2) ? m4.z : m4.w;
            const bool keep = (mv != 0) && (!diag || (kg0 + r <= qr));
            p[r] = keep ? e : 0.f;
          }
          const uint2 d = {pack_bf16(p[0], p[1]), pack_bf16(p[2], p[3])};
          *(uint2*)&myP[(sub * 16 + l16) * LK + kl0] = d;
        }
      }
    }

    // ---- P A-frags (wave-private round-trip), L via ones-MFMA, PV
    union { short8 v; uint4 q; } pf[2][2];
#pragma unroll
    for (int sub = 0; sub < 2; ++sub) {
      const unsigned short* p0 = &myP[(sub * 16 + l16) * LK + quad * 8];
      pf[sub][0].q = *(const uint4*)p0;
      pf[sub][1].q = *(const uint4*)(p0 + 32);
      Lacc[sub] = __builtin_amdgcn_mfma_f32_16x16x32_bf16(pf[sub][0].v, onesB, Lacc[sub], 0, 0, 0);
      Lacc[sub] = __builtin_amdgcn_mfma_f32_16x16x32_bf16(pf[sub][1].v, onesB, Lacc[sub], 0, 0, 0);
    }
    __builtin_amdgcn_s_setprio(1);
#pragma unroll
    for (int dc = 0; dc < 4; ++dc) {
      union { short8 v; uint4 q; } vf[2];
      const unsigned short* p0 = &Vt[(dc * 16 + l16) * LK + quad * 8];
      vf[0].q = *(const uint4*)p0;
      vf[1].q = *(const uint4*)(p0 + 32);
#pragma unroll
      for (int sub = 0; sub < 2; ++sub) {
        O[sub][dc] = __builtin_amdgcn_mfma_f32_16x16x32_bf16(pf[sub][0].v, vf[0].v, O[sub][dc], 0, 0, 0);
        O[sub][dc] = __builtin_amdgcn_mfma_f32_16x16x32_bf16(pf[sub][1].v, vf[1].v, O[sub][dc], 0, 0, 0);
      }
    }
    __builtin_amdgcn_s_setprio(0);
    __syncthreads();   // all waves done reading Kt/Vt before next ds_write
  }

  // write partials (unnormalized, m==0): 128 rows x 64 per slot
  const size_t slot = (size_t)h * 80 + x;
#pragma unroll
  for (int sub = 0; sub < 2; ++sub) {
#pragma unroll
    for (int dc = 0; dc < 4; ++dc)
#pragma unroll
      for (int r = 0; r < 4; ++r)
        Opart[slot * 8192 + (w * 32 + sub * 16 + quad * 4 + r) * 64 + dc * 16 + l16] =
            f2bf(O[sub][dc][r]);
    if (l16 == 0) {
#pragma unroll
      for (int r = 0; r < 4; ++r)
        Lpart[slot * 128 + w * 32 + sub * 16 + quad * 4 + r] = Lacc[sub][r];
    }
  }
}

// merge <=4 partials per (qt128, h): thread -> (q-row, 32-wide d-half)
__global__ __launch_bounds__(256) void k_attn_merge(
    const unsigned short* __restrict__ Opart, const float* __restrict__ Lpart,
    unsigned short* __restrict__ ob) {
  const int qt = blockIdx.x, h = blockIdx.y;   // qt in [0,32)
  const int t = threadIdx.x;
  const int row = t >> 1, half = (t & 1) * 32;
  const int g = qt >> 3;
  const int nch = g + 1;
  const int cb = h * 80 + 4 * g * (g + 1) + (qt & 7) * (g + 1);
  float L = 0.f;
  float acc[32];
#pragma unroll
  for (int j = 0; j < 32; ++j) acc[j] = 0.f;
  for (int ci = 0; ci < nch; ++ci) {
    L += Lpart[(size_t)(cb + ci) * 128 + row];
    const unsigned short* op = Opart + (size_t)(cb + ci) * 8192 + row * 64 + half;
#pragma unroll
    for (int j4 = 0; j4 < 4; ++j4) {
      union { uint4 v; unsigned short e[8]; } u;
      u.v = *(const uint4*)(op + j4 * 8);
#pragma unroll
      for (int e = 0; e < 8; ++e) acc[j4 * 8 + e] += bf2f(u.e[e]);
    }
  }
  const float inv = 1.f / L;
  unsigned short* orow = ob + (size_t)(qt * 128 + row) * D_ + h * HD_ + half;
#pragma unroll
  for (int j4 = 0; j4 < 4; ++j4) {
    union { uint4 v; unsigned short e[8]; } u;
#pragma unroll
    for (int e = 0; e < 8; ++e) u.e[e] = f2bf(acc[j4 * 8 + e] * inv);
    *(uint4*)(orow + j4 * 8) = u.v;
  }
}

// ---------------- host
extern "C" void kernel_launch(void* const* d_in, const int* in_sizes, int n_in,
                              void* d_out, int out_size, void* d_ws, size_t ws_size,
                              hipStream_t stream) {
  const void* hidden = d_in[0];
  const int*  amask  = (const int*)d_in[1];
  const void* ln1w = d_in[2];  const void* ln1b = d_in[3];
  const void* wq   = d_in[4];  const void* bq   = d_in[5];
  const void* wk   = d_in[6];  const void* bk   = d_in[7];
  const void* wv   = d_in[8];  const void* bv   = d_in[9];
  const void* wo   = d_in[10]; const void* bo   = d_in[11];
  const void* ln2w = d_in[12]; const void* ln2b = d_in[13];
  const void* wup  = d_in[14]; const void* bup  = d_in[15];
  const void* wdn  = d_in[16]; const void* bdn  = d_in[17];

  char* ws = (char*)d_ws;
  size_t off = 0;
  auto alloc = [&](size_t bytes) {
    char* p = ws + off;
    off += (bytes + 255) & ~(size_t)255;
    return p;
  };
  const size_t SD = (size_t)SD_;
  int*            flagp = (int*)alloc(4);
  float*          h1    = (float*)alloc(SD * 4);
  float*          prm   = (float*)alloc(9984 * 4);
  float*          h2    = (float*)alloc(SD * 4);            // also hosts attn partials
  unsigned short* xb    = (unsigned short*)alloc(SD * 2);   // contiguous after h2
  unsigned short* wqkvt = (unsigned short*)alloc((size_t)2304 * 768 * 2);  // [2304][768]
  unsigned short* wot   = (unsigned short*)alloc((size_t)768 * 768 * 2);   // [768][768]
  unsigned short* wupt  = (unsigned short*)alloc((size_t)3072 * 768 * 2);  // [3072][768]
  unsigned short* wdnt  = (unsigned short*)alloc((size_t)768 * 3072 * 2);  // [768][3072]
  unsigned short* big   = (unsigned short*)alloc((size_t)S_ * FF_ * 2);
  unsigned short* qb2 = big;
  unsigned short* kb2 = big + SD;
  unsigned short* vtb = big + 2 * SD;   // V^T [768][4096]
  unsigned short* ab  = big + 3 * SD;
  unsigned short* ffb = big;
  // attention partials overlay dead h2+xb (18.87 MB): Opart 960*8192 bf16 =
  // 15.73 MB + Lpart 960*128 f32 = 0.49 MB = 16.22 MB. FITS.
  unsigned short* Opart = (unsigned short*)h2;
  float*          Lpart = (float*)((char*)h2 + (size_t)960 * 8192 * 2);
  // down-GEMM bf16 partials [2][4096][768] also live in h2 (dead after ln2;
  // 2 * 6.29 MB = 12.58 MB = exactly h2)
  unsigned short* Dpart = (unsigned short*)h2;

  float* f_ln1w = prm;        float* f_ln1b = prm + 768;
  float* f_ln2w = prm + 1536; float* f_ln2b = prm + 2304;
  float* f_bqkv = prm + 3072; float* f_bo = prm + 5376;
  float* f_bdn = prm + 6144;  float* f_bup = prm + 6912;

  k_cvt_params<<<39, 256, 0, stream>>>(ln1w, ln1b, ln2w, ln2b, bq, bk, bv, bo, bdn, bup,
                                       prm, flagp);
  k_cvt_t6<<<1728, 256, 0, stream>>>(wq, wk, wv, wo, wup, wdn,
                                     wqkvt, wqkvt + 768 * 768, wqkvt + 2 * 768 * 768,
                                     wot, wupt, wdnt, flagp);

  // ln1 fused with input convert: reads raw hidden (flag dtype), writes
  // xb (LN output) + h1 (f32 copy of hidden, O-proj residual)
  k_ln<<<S_, 256, 0, stream>>>(hidden, flagp, f_ln1w, f_ln1b, xb, h1, nullptr, nullptr);

  // fused QKV: [4096,768] @ [768,2304] -> scatter Q(scaled),K,V^T
  // <64,128>: (18,64) = 1152 blocks %8==0, 24KB LDS
  k_gemm_t<64, 128><<<dim3(18, 64), 256, 0, stream>>>(
      xb, wqkvt, f_bqkv, nullptr, qb2, S_, 2304, 768, 5, flagp);

  k_attn_chunk<<<dim3(80, 12), 256, 0, stream>>>(qb2, kb2, vtb, amask, Opart, Lpart);
  k_attn_merge<<<dim3(32, 12), 256, 0, stream>>>(Opart, Lpart, ab);

  // O-proj + residual -> h2 (f32)   <64,64>: (12,64) = 768 blocks %8==0
  k_gemm_t<64, 64><<<dim3(12, 64), 256, 0, stream>>>(
      ab, wot, f_bo, h1, h2, S_, 768, 768, 1, flagp);

  // ln2 (h2 is f32: flagp=nullptr); h1 dead -> pre-init acc = h2 + b_down
  k_ln<<<S_, 256, 0, stream>>>(h2, nullptr, f_ln2w, f_ln2b, xb, nullptr, f_bdn, h1);

  // FFN up   <64,128>: (24,64) = 1536 blocks %8==0, 24KB LDS
  k_gemm_t<64, 128><<<dim3(24, 64), 256, 0, stream>>>(
      xb, wupt, f_bup, nullptr, ffb, S_, 3072, 768, 2, flagp);

  // FFN down <64,64> split-K=2, mode 7: NON-atomic bf16 partials into h2
  // (dead after ln2). (12,64,2) = 1536 blocks %8==0; each (row,col,z)
  // written exactly once -> no init, no RMW.
  k_gemm_t<64, 64><<<dim3(12, 64, 2), 256, 0, stream>>>(
      ffb, wdnt, nullptr, nullptr, Dpart, S_, 768, 3072, 7, flagp);

  // out = h1acc(h2+bdn) + p0 + p1, per dtype flag
  k_out<<<3072, 256, 0, stream>>>(h1, Dpart, flagp, d_out);
}